// Round 1
// baseline (875.414 us; speedup 1.0000x reference)
//
#include <hip/hip_runtime.h>
#include <math.h>

#define NB 2

__device__ __forceinline__ float gelu_exact(float x) {
    return 0.5f * x * (1.0f + erff(x * 0.70710678118654752f));
}

__global__ __launch_bounds__(192)
void fisher_axial_kernel(const float* __restrict__ z,
                         const float* __restrict__ w1r, const float* __restrict__ b1r,
                         const float* __restrict__ w2r, const float* __restrict__ b2r,
                         const float* __restrict__ w1c, const float* __restrict__ b1c,
                         const float* __restrict__ w2c, const float* __restrict__ b2c,
                         const float* __restrict__ w1b, const float* __restrict__ b1b,
                         const float* __restrict__ w2b, const float* __restrict__ b2b,
                         const float* __restrict__ gw, const float* __restrict__ gb,
                         const float* __restrict__ alphap,
                         float* __restrict__ out)
{
    // smem layout (floats): zs[NB][5184] | up[NB][3][576] | hbb[NB][1728] (h, then bb)
    __shared__ __align__(16) float smem[NB*5184 + NB*1728 + NB*1728];
    constexpr int UP = NB*5184;
    constexpr int HB = NB*5184 + NB*1728;

    const int t    = threadIdx.x;
    const int lane = t & 63;
    const int m    = t >> 6;            // 0=row, 1=col, 2=box (wave-uniform)
    const int lb   = lane >> 5;         // local batch element (0/1) in lane dim
    const int o2   = (lane & 31) * 2;   // two output features per thread
    const int b0   = blockIdx.x * NB;
    const float alpha = alphap[0];

    // ---- load z tile: NB*5184 floats ----
    {
        const float4* zin = (const float4*)(z + (size_t)b0 * 5184);
        float4* zd = (float4*)smem;
        for (int idx = t; idx < NB*5184/4; idx += 192)
            zd[idx] = zin[idx];
    }
    __syncthreads();

    const float* w1 = (m == 0) ? w1r : (m == 1) ? w1c : w1b;
    const float* b1 = (m == 0) ? b1r : (m == 1) ? b1c : b1b;
    const float* w2 = (m == 0) ? w2r : (m == 1) ? w2c : w2b;
    const float* b2 = (m == 0) ? b2r : (m == 1) ? b2c : b2b;

    // ---- stage 1: h = gelu(ctx @ w1 + b1), ctx gathered from zs per MLP ----
    {
        int istr[9];
        #pragma unroll
        for (int i = 0; i < 9; ++i)
            istr[i] = (m == 0) ? i*576 : (m == 1) ? i*64 : (i/3)*1728 + (i%3)*192;
        const int zbase = lb * 5184;

        float acc[9][2];
        #pragma unroll
        for (int i = 0; i < 9; ++i) { acc[i][0] = 0.f; acc[i][1] = 0.f; }

        for (int k = 0; k < 576; k += 4) {
            const int cell = k >> 6, d = k & 63;
            const int coff = (m == 0) ? k
                           : (m == 1) ? cell*576 + d
                           :            (cell/3)*576 + (cell%3)*64 + d;
            const float2 wa = *(const float2*)&w1[(k+0)*64 + o2];
            const float2 wb = *(const float2*)&w1[(k+1)*64 + o2];
            const float2 wc = *(const float2*)&w1[(k+2)*64 + o2];
            const float2 wd = *(const float2*)&w1[(k+3)*64 + o2];
            #pragma unroll
            for (int i = 0; i < 9; ++i) {
                const float4 v = *(const float4*)&smem[zbase + istr[i] + coff];
                acc[i][0] = fmaf(v.x, wa.x, fmaf(v.y, wb.x, fmaf(v.z, wc.x, fmaf(v.w, wd.x, acc[i][0]))));
                acc[i][1] = fmaf(v.x, wa.y, fmaf(v.y, wb.y, fmaf(v.z, wc.y, fmaf(v.w, wd.y, acc[i][1]))));
            }
        }
        const float2 b1v = *(const float2*)&b1[o2];
        #pragma unroll
        for (int i = 0; i < 9; ++i) {
            const float h0 = gelu_exact(acc[i][0] + b1v.x);
            const float h1 = gelu_exact(acc[i][1] + b1v.y);
            *(float2*)&smem[HB + lb*1728 + (m*9 + i)*64 + o2] = make_float2(h0, h1);
        }
    }
    __syncthreads();

    // ---- stage 2: up = h @ w2 + b2 ----
    {
        const float2 b2v = *(const float2*)&b2[o2];
        #pragma unroll
        for (int i = 0; i < 9; ++i) {
            float a0 = 0.f, a1 = 0.f;
            const int hbase = HB + lb*1728 + (m*9 + i)*64;
            #pragma unroll
            for (int k = 0; k < 64; k += 4) {
                const float4 h4 = *(const float4*)&smem[hbase + k];
                const float2 wa = *(const float2*)&w2[(k+0)*64 + o2];
                const float2 wb = *(const float2*)&w2[(k+1)*64 + o2];
                const float2 wc = *(const float2*)&w2[(k+2)*64 + o2];
                const float2 wd = *(const float2*)&w2[(k+3)*64 + o2];
                a0 = fmaf(h4.x, wa.x, fmaf(h4.y, wb.x, fmaf(h4.z, wc.x, fmaf(h4.w, wd.x, a0))));
                a1 = fmaf(h4.x, wa.y, fmaf(h4.y, wb.y, fmaf(h4.z, wc.y, fmaf(h4.w, wd.y, a1))));
            }
            *(float2*)&smem[UP + lb*1728 + m*576 + i*64 + o2] = make_float2(a0 + b2v.x, a1 + b2v.y);
        }
    }
    __syncthreads();

    // ---- bb: permuted box-broadcast vectors bb[b][R][C%3][d'] = up2[b][R][(64*(C%3)+d')/3] ----
    for (int idx = t; idx < NB*1728; idx += 192) {
        const int b   = idx / 1728;
        const int r2  = idx % 1728;
        const int R   = r2 / 192;
        const int rem = r2 % 192;
        const int cm3 = rem >> 6, dp = rem & 63;
        smem[HB + idx] = smem[UP + b*1728 + 2*576 + R*64 + (cm3*64 + dp)/3];
    }
    __syncthreads();

    // ---- gate GEMM + epilogue: wave m handles cells [m*27, m*27+27) for both b ----
    {
        float acc0[27], acc1[27];
        #pragma unroll
        for (int j = 0; j < 27; ++j) { acc0[j] = 0.f; acc1[j] = 0.f; }

        #pragma unroll
        for (int seg = 0; seg < 3; ++seg) {
            int base[27];
            #pragma unroll
            for (int j = 0; j < 27; ++j) {
                const int R = 3*m + j/9;     // cell = m*27 + j, R = cell/9
                const int C = j % 9;
                base[j] = (seg == 0) ? UP + lb*1728 + R*64
                        : (seg == 1) ? UP + lb*1728 + 576 + C*64
                        :              HB + lb*1728 + R*192 + (C % 3)*64;
            }
            const float* gwp = gw + seg*64*64;
            for (int k = 0; k < 64; k += 4) {
                const float2 wa = *(const float2*)&gwp[(k+0)*64 + o2];
                const float2 wb = *(const float2*)&gwp[(k+1)*64 + o2];
                const float2 wc = *(const float2*)&gwp[(k+2)*64 + o2];
                const float2 wd = *(const float2*)&gwp[(k+3)*64 + o2];
                #pragma unroll
                for (int j = 0; j < 27; ++j) {
                    const float4 v = *(const float4*)&smem[base[j] + k];
                    acc0[j] = fmaf(v.x, wa.x, fmaf(v.y, wb.x, fmaf(v.z, wc.x, fmaf(v.w, wd.x, acc0[j]))));
                    acc1[j] = fmaf(v.x, wa.y, fmaf(v.y, wb.y, fmaf(v.z, wc.y, fmaf(v.w, wd.y, acc1[j]))));
                }
            }
        }

        const float2 gbv = *(const float2*)&gb[o2];
        float* outb = out + (size_t)(b0 + lb) * 5184;
        #pragma unroll
        for (int j = 0; j < 27; ++j) {
            const int cell = m*27 + j;
            const int R = 3*m + j/9, C = j % 9, cm3 = C % 3;
            const int u0 = UP + lb*1728 + R*64 + o2;
            const int u1 = UP + lb*1728 + 576 + C*64 + o2;
            const int u2 = HB + lb*1728 + R*192 + cm3*64 + o2;
            const float d0 = smem[u0]   + smem[u1]   + smem[u2];
            const float d1 = smem[u0+1] + smem[u1+1] + smem[u2+1];
            const float g0 = 1.f / (1.f + expf(-(acc0[j] + gbv.x)));
            const float g1 = 1.f / (1.f + expf(-(acc1[j] + gbv.y)));
            const float z0 = smem[lb*5184 + cell*64 + o2];
            const float z1 = smem[lb*5184 + cell*64 + o2 + 1];
            *(float2*)&outb[cell*64 + o2] = make_float2(z0 + alpha*g0*d0, z1 + alpha*g1*d1);
        }
    }
}

extern "C" void kernel_launch(void* const* d_in, const int* in_sizes, int n_in,
                              void* d_out, int out_size, void* d_ws, size_t ws_size,
                              hipStream_t stream) {
    const float* z   = (const float*)d_in[0];
    const float* w1r = (const float*)d_in[1];
    const float* b1r = (const float*)d_in[2];
    const float* w2r = (const float*)d_in[3];
    const float* b2r = (const float*)d_in[4];
    const float* w1c = (const float*)d_in[5];
    const float* b1c = (const float*)d_in[6];
    const float* w2c = (const float*)d_in[7];
    const float* b2c = (const float*)d_in[8];
    const float* w1b = (const float*)d_in[9];
    const float* b1b = (const float*)d_in[10];
    const float* w2b = (const float*)d_in[11];
    const float* b2b = (const float*)d_in[12];
    const float* gw  = (const float*)d_in[13];
    const float* gb  = (const float*)d_in[14];
    const float* al  = (const float*)d_in[15];
    float* outp = (float*)d_out;

    const int Btot = in_sizes[0] / 5184;   // 8192
    fisher_axial_kernel<<<Btot / NB, 192, 0, stream>>>(
        z, w1r, b1r, w2r, b2r, w1c, b1c, w2c, b2c,
        w1b, b1b, w2b, b2b, gw, gb, al, outp);
}

// Round 2
// 385.474 us; speedup vs baseline: 2.2710x; 2.2710x over previous
//
#include <hip/hip_runtime.h>
#include <hip/hip_bf16.h>

typedef __attribute__((ext_vector_type(8))) short short8;
typedef __attribute__((ext_vector_type(4))) float f32x4;

__device__ __forceinline__ unsigned short f2bf(float f) {
    union { __hip_bfloat16 b; unsigned short u; } v;
    v.b = __float2bfloat16(f);
    return v.u;
}
__device__ __forceinline__ float bf2f(unsigned short u) {
    return __uint_as_float(((unsigned)u) << 16);
}
__device__ __forceinline__ float gelu_tanh(float x) {
    float u = 0.79788456080286536f * x * (1.0f + 0.044715f * x * x);
    // 0.5*(1+tanh(u)) = 1/(1+exp(-2u)) = rcp(1 + exp2(-2*log2e*u))
    return x * __builtin_amdgcn_rcpf(1.0f + __builtin_exp2f(-2.8853900817779268f * u));
}
__device__ __forceinline__ float sigmoidf(float x) {
    return __builtin_amdgcn_rcpf(1.0f + __builtin_exp2f(-1.4426950408889634f * x));
}
// swizzled LDS offset (in shorts): XOR row bits into 16B-slot bits
__device__ __forceinline__ int swz(int row, int col) {
    return (row * 64 + col) ^ ((row & 7) << 3);
}

// ---------------- prepack: fp32 weights -> bf16 MFMA B-fragment layout in ws ----------------
// layout (shorts): W1[m] at m*36864 ; W2[m] at 110592+m*4096 ; GATE(320x64 eff.) at 122880
__global__ __launch_bounds__(256)
void prepack_kernel(const float* __restrict__ w1r, const float* __restrict__ w1c,
                    const float* __restrict__ w1b,
                    const float* __restrict__ w2r, const float* __restrict__ w2c,
                    const float* __restrict__ w2b,
                    const float* __restrict__ gw, unsigned short* __restrict__ ws)
{
    int t = blockIdx.x * 256 + threadIdx.x;
    if (t < 13824) {                       // w1 x3 : K=576 -> 18 ksteps
        int wi = t / 4608, r = t % 4608;
        const float* src = (wi == 0) ? w1r : (wi == 1) ? w1c : w1b;
        unsigned short* dst = ws + wi * 36864;
        int lane = r & 63;
        int col = ((r >> 6) & 3) * 16 + (lane & 15);
        int k0 = (r >> 8) * 32 + (lane >> 4) * 8;
        #pragma unroll
        for (int j = 0; j < 8; ++j) dst[r * 8 + j] = f2bf(src[(k0 + j) * 64 + col]);
    } else if (t < 15360) {                // w2 x3 : K=64 -> 2 ksteps
        int q = t - 13824, wi = q / 512, r = q % 512;
        const float* src = (wi == 0) ? w2r : (wi == 1) ? w2c : w2b;
        unsigned short* dst = ws + 110592 + wi * 4096;
        int lane = r & 63;
        int col = ((r >> 6) & 3) * 16 + (lane & 15);
        int k0 = (r >> 8) * 32 + (lane >> 4) * 8;
        #pragma unroll
        for (int j = 0; j < 8; ++j) dst[r * 8 + j] = f2bf(src[(k0 + j) * 64 + col]);
    } else if (t < 17920) {                // gate: rows 0-127 as-is, 128+ : 3 summed box variants
        int r = t - 15360;
        unsigned short* dst = ws + 122880;
        int lane = r & 63;
        int col = ((r >> 6) & 3) * 16 + (lane & 15);
        int k0 = (r >> 8) * 32 + (lane >> 4) * 8;
        #pragma unroll
        for (int j = 0; j < 8; ++j) {
            int krow = k0 + j;
            float v;
            if (krow < 128) {
                v = gw[krow * 64 + col];
            } else {
                int c = (krow - 128) >> 6, e = (krow - 128) & 63;
                int lo = 3 * e - 64 * c;
                v = 0.f;
                #pragma unroll
                for (int s = 0; s < 3; ++s) {
                    int dp = lo + s;
                    if (dp >= 0 && dp < 64) v += gw[(128 + dp) * 64 + col];
                }
            }
            dst[r * 8 + j] = f2bf(v);
        }
    }
}

// ---------------- main fused kernel: 16 batch elements / block, 9 waves ----------------
__global__ __launch_bounds__(576, 5)
void fisher_mfma_kernel(const float* __restrict__ z,
                        const float* __restrict__ b1r, const float* __restrict__ b2r,
                        const float* __restrict__ b1c, const float* __restrict__ b2c,
                        const float* __restrict__ b1b, const float* __restrict__ b2b,
                        const float* __restrict__ gb, const float* __restrict__ alphap,
                        const short* __restrict__ wsp,
                        float* __restrict__ out)
{
    // H: 9 waves * 16x64 ; UPR/UPC/UPB: 144x64 each (bf16, swizzled)
    __shared__ __align__(16) unsigned short lds[36864];
    const int tid = threadIdx.x;
    const int lane = tid & 63;
    const int wave = tid >> 6;          // 0..8
    const int rl = lane & 15;
    const int kg = lane >> 4;           // 0..3
    const int koff = kg * 8;
    const int b0 = blockIdx.x * 16;
    const int m = wave / 3;             // 0=row 1=col 2=box ; also gate variant c
    const int sw = wave % 3;

    const short* w1p = wsp + m * 36864;
    const short* w2p = wsp + 110592 + m * 4096;
    const float* b1p = (m == 0) ? b1r : (m == 1) ? b1c : b1b;
    const float* b2p = (m == 0) ? b2r : (m == 1) ? b2c : b2b;

    // ---- stage 1: ctx @ w1 over 3 M-tiles, K-outer ----
    int abase[3];
    #pragma unroll
    for (int tt = 0; tt < 3; ++tt) {
        int r = sw * 48 + tt * 16 + rl;
        int lb = r / 9, i = r % 9;
        int ib = (m == 0) ? i * 576 : (m == 1) ? i * 64 : (i / 3) * 1728 + (i % 3) * 192;
        abase[tt] = (b0 + lb) * 5184 + ib;
    }

    f32x4 acc[3][4];
    #pragma unroll
    for (int tt = 0; tt < 3; ++tt)
        #pragma unroll
        for (int nt = 0; nt < 4; ++nt) acc[tt][nt] = (f32x4)0.f;

    static const int boxoff[9] = {0, 64, 128, 576, 640, 704, 1152, 1216, 1280};

    #pragma unroll
    for (int kk = 0; kk < 18; ++kk) {
        const int cell = kk >> 1;
        const int dof = (kk & 1) * 32 + koff;
        const int coff = (m == 0) ? cell * 64 : (m == 1) ? cell * 576 : boxoff[cell];
        short8 a[3];
        #pragma unroll
        for (int tt = 0; tt < 3; ++tt) {
            const float* ap = z + abase[tt] + coff + dof;
            float4 f0 = *(const float4*)ap;
            float4 f1 = *(const float4*)(ap + 4);
            short8 av;
            av[0] = (short)f2bf(f0.x); av[1] = (short)f2bf(f0.y);
            av[2] = (short)f2bf(f0.z); av[3] = (short)f2bf(f0.w);
            av[4] = (short)f2bf(f1.x); av[5] = (short)f2bf(f1.y);
            av[6] = (short)f2bf(f1.z); av[7] = (short)f2bf(f1.w);
            a[tt] = av;
        }
        #pragma unroll
        for (int nt = 0; nt < 4; ++nt) {
            short8 bv = *(const short8*)(w1p + ((kk * 4 + nt) * 64 + lane) * 8);
            #pragma unroll
            for (int tt = 0; tt < 3; ++tt)
                acc[tt][nt] = __builtin_amdgcn_mfma_f32_16x16x32_bf16(a[tt], bv, acc[tt][nt], 0, 0, 0);
        }
    }

    float b1v[4], b2v[4];
    #pragma unroll
    for (int nt = 0; nt < 4; ++nt) { b1v[nt] = b1p[nt * 16 + rl]; b2v[nt] = b2p[nt * 16 + rl]; }
    const int upoff = (m == 0) ? 9216 : (m == 1) ? 18432 : 27648;
    const int hoff = wave * 1024;

    // ---- per tile: gelu -> H (LDS) -> stage 2 -> UP (LDS). All same-wave, no barrier. ----
    #pragma unroll
    for (int tt = 0; tt < 3; ++tt) {
        asm volatile("s_waitcnt lgkmcnt(0)" ::: "memory");   // WAR vs prev tile's H reads
        #pragma unroll
        for (int nt = 0; nt < 4; ++nt)
            #pragma unroll
            for (int reg = 0; reg < 4; ++reg) {
                int hrow = kg * 4 + reg, col = nt * 16 + rl;
                lds[hoff + swz(hrow, col)] = f2bf(gelu_tanh(acc[tt][nt][reg] + b1v[nt]));
            }
        asm volatile("s_waitcnt lgkmcnt(0)" ::: "memory");   // RAW: H visible to whole wave
        f32x4 acc2[4];
        #pragma unroll
        for (int nt = 0; nt < 4; ++nt) acc2[nt] = (f32x4)0.f;
        #pragma unroll
        for (int kk2 = 0; kk2 < 2; ++kk2) {
            short8 a2 = *(const short8*)&lds[hoff + swz(rl, kk2 * 32 + koff)];
            #pragma unroll
            for (int nt = 0; nt < 4; ++nt) {
                short8 bw = *(const short8*)(w2p + ((kk2 * 4 + nt) * 64 + lane) * 8);
                acc2[nt] = __builtin_amdgcn_mfma_f32_16x16x32_bf16(a2, bw, acc2[nt], 0, 0, 0);
            }
        }
        #pragma unroll
        for (int nt = 0; nt < 4; ++nt)
            #pragma unroll
            for (int reg = 0; reg < 4; ++reg) {
                int row = sw * 48 + tt * 16 + kg * 4 + reg;
                int col = nt * 16 + rl;
                lds[upoff + swz(row, col)] = f2bf(acc2[nt][reg] + b2v[nt]);
            }
    }
    __syncthreads();

    // ---- gate GEMM (K=192 -> 6 ksteps, box seg uses summed variant c=m) + epilogue ----
    float gbv[4];
    #pragma unroll
    for (int nt = 0; nt < 4; ++nt) gbv[nt] = gb[nt * 16 + rl];
    const float alpha = alphap[0];
    const short* gwp = wsp + 122880;
    const int c = m;

    for (int pass = 0; pass < 3; ++pass) {
        const int tiles0 = sw * 9 + pass * 3;
        int rR[3], rC[3];
        #pragma unroll
        for (int tt = 0; tt < 3; ++tt) {
            int r = (tiles0 + tt) * 16 + rl;
            int lb = r / 27, j = r % 27;
            rR[tt] = lb * 9 + j / 3;
            rC[tt] = lb * 9 + c + 3 * (j % 3);
        }
        f32x4 ag[3][4];
        #pragma unroll
        for (int tt = 0; tt < 3; ++tt)
            #pragma unroll
            for (int nt = 0; nt < 4; ++nt) ag[tt][nt] = (f32x4)0.f;

        #pragma unroll
        for (int s6 = 0; s6 < 6; ++s6) {
            const int kkp = (s6 < 4) ? s6 : 4 + 2 * c + (s6 - 4);
            const int ko = (s6 & 1) * 32 + koff;
            const int region = (s6 < 2) ? 9216 : (s6 < 4) ? 18432 : 27648;
            short8 a[3];
            #pragma unroll
            for (int tt = 0; tt < 3; ++tt) {
                int lr = (s6 >= 2 && s6 < 4) ? rC[tt] : rR[tt];
                a[tt] = *(const short8*)&lds[region + swz(lr, ko)];
            }
            #pragma unroll
            for (int nt = 0; nt < 4; ++nt) {
                short8 bv = *(const short8*)(gwp + ((kkp * 4 + nt) * 64 + lane) * 8);
                #pragma unroll
                for (int tt = 0; tt < 3; ++tt)
                    ag[tt][nt] = __builtin_amdgcn_mfma_f32_16x16x32_bf16(a[tt], bv, ag[tt][nt], 0, 0, 0);
            }
        }
        // epilogue: sigmoid(gate) ; delta from LDS ; out = z + alpha*g*delta
        #pragma unroll
        for (int tt = 0; tt < 3; ++tt)
            #pragma unroll
            for (int reg = 0; reg < 4; ++reg) {
                int r = (tiles0 + tt) * 16 + kg * 4 + reg;
                int lb = r / 27, j = r % 27;
                int R = j / 3, C = c + 3 * (j % 3);
                size_t zoff = (size_t)(b0 + lb) * 5184 + (size_t)(R * 9 + C) * 64;
                int rowR = lb * 9 + R, rowC = lb * 9 + C;
                #pragma unroll
                for (int nt = 0; nt < 4; ++nt) {
                    int d = nt * 16 + rl;
                    float g = sigmoidf(ag[tt][nt][reg] + gbv[nt]);
                    float du = bf2f(lds[9216 + swz(rowR, d)]);
                    float dc = bf2f(lds[18432 + swz(rowC, d)]);
                    float db = bf2f(lds[27648 + swz(rowR, (64 * c + d) / 3)]);
                    float zv = z[zoff + d];
                    out[zoff + d] = zv + alpha * g * (du + dc + db);
                }
            }
    }
}

extern "C" void kernel_launch(void* const* d_in, const int* in_sizes, int n_in,
                              void* d_out, int out_size, void* d_ws, size_t ws_size,
                              hipStream_t stream) {
    const float* z   = (const float*)d_in[0];
    const float* w1r = (const float*)d_in[1];
    const float* b1r = (const float*)d_in[2];
    const float* w2r = (const float*)d_in[3];
    const float* b2r = (const float*)d_in[4];
    const float* w1c = (const float*)d_in[5];
    const float* b1c = (const float*)d_in[6];
    const float* w2c = (const float*)d_in[7];
    const float* b2c = (const float*)d_in[8];
    const float* w1b = (const float*)d_in[9];
    const float* b1b = (const float*)d_in[10];
    const float* w2b = (const float*)d_in[11];
    const float* b2b = (const float*)d_in[12];
    const float* gw  = (const float*)d_in[13];
    const float* gb  = (const float*)d_in[14];
    const float* al  = (const float*)d_in[15];
    float* outp = (float*)d_out;
    unsigned short* ws = (unsigned short*)d_ws;

    prepack_kernel<<<70, 256, 0, stream>>>(w1r, w1c, w1b, w2r, w2c, w2b, gw, ws);

    const int Btot = in_sizes[0] / 5184;    // 8192
    fisher_mfma_kernel<<<Btot / 16, 576, 0, stream>>>(
        z, b1r, b2r, b1c, b2c, b1b, b2b, gb, al, (const short*)ws, outp);
}